// Round 1
// baseline (2701.126 us; speedup 1.0000x reference)
//
#include <hip/hip_runtime.h>

// ParallelLinear: out[e,o,t] = sum_n W[e,o,n] * x[e,n,t] + b[e,o]
// E=10000, N=64, O=64, T=256, all fp32.
// One block per edge; thread t owns output column t.
// x column lives in 64 VGPRs; W rows / bias are block-uniform -> scalar loads.

#define N_IN    64
#define O_OUT   64
#define T_STEPS 256

__global__ __launch_bounds__(256, 4) void ParallelLinear_77627238908437_kernel(
    const float* __restrict__ x,   // [E, N, T]
    const float* __restrict__ W,   // [E, O, N]
    const float* __restrict__ b,   // [E, O]
    float* __restrict__ out)       // [E, O, T]
{
    const int e = blockIdx.x;
    const int t = threadIdx.x;

    const float* __restrict__ xe   = x   + (size_t)e * (N_IN * T_STEPS);
    const float* __restrict__ We   = W   + (size_t)e * (O_OUT * N_IN);
    const float* __restrict__ be   = b   + (size_t)e * O_OUT;
    float* __restrict__       oute = out + (size_t)e * (O_OUT * T_STEPS);

    // Load this thread's x column into registers: coalesced (lane t -> addr n*T + t).
    float xr[N_IN];
#pragma unroll
    for (int n = 0; n < N_IN; ++n) {
        xr[n] = xe[n * T_STEPS + t];
    }

    // For each output row o: dot(W[o,:], xr) + b[o].
    // W/b addresses are uniform across the block -> scalar loads (SGPRs),
    // consumed directly by v_fmac_f32.
#pragma unroll 4
    for (int o = 0; o < O_OUT; ++o) {
        const float* __restrict__ Wrow = We + o * N_IN;
        float acc = be[o];
#pragma unroll
        for (int n = 0; n < N_IN; ++n) {
            acc = fmaf(Wrow[n], xr[n], acc);
        }
        oute[o * T_STEPS + t] = acc;
    }
}

extern "C" void kernel_launch(void* const* d_in, const int* in_sizes, int n_in,
                              void* d_out, int out_size, void* d_ws, size_t ws_size,
                              hipStream_t stream) {
    const float* x = (const float*)d_in[0];
    const float* W = (const float*)d_in[1];
    const float* b = (const float*)d_in[2];
    float* out = (float*)d_out;

    const int E = in_sizes[0] / (N_IN * T_STEPS);  // 10000

    dim3 grid(E);
    dim3 block(T_STEPS);
    ParallelLinear_77627238908437_kernel<<<grid, block, 0, stream>>>(x, W, b, out);
}